// Round 3
// baseline (6003.801 us; speedup 1.0000x reference)
//
#include <hip/hip_runtime.h>
#include <math.h>
#include <stdint.h>

#define NT 32768
#define DM 1024
#define NC 4096
#define CD 256

#define X_F4 (DM/4)
#define W_F4 (CD/4)
#define Z_F4 (CD/4)
#define C_F4 (CD/4)

#define GLOBAL_AS __attribute__((address_space(1)))
#define LDS_AS    __attribute__((address_space(3)))

typedef __attribute__((ext_vector_type(8))) short bf16x8;
typedef __attribute__((ext_vector_type(4))) float floatx4;

__device__ __forceinline__ unsigned short f2bf(float f) {
    union { float f; uint32_t u; } v; v.f = f;
    uint32_t u = v.u;
    u += 0x7FFFu + ((u >> 16) & 1u);   // RN-even
    return (unsigned short)(u >> 16);
}

// ---------------------------------------------------------------------------
// K0: per-code prep: hn2[code] = 0.5*||c||^2 - 2, bf16 codebook copy.
// ---------------------------------------------------------------------------
__global__ __launch_bounds__(256) void k0_prep(const float4* __restrict__ cb,
                                               float* __restrict__ hn2,
                                               ushort* __restrict__ cbb) {
    int wid = threadIdx.x >> 6, lane = threadIdx.x & 63;
    int code = blockIdx.x * 4 + wid;
    float4 c = cb[(size_t)code * C_F4 + lane];
    ushort4 h;
    h.x = f2bf(c.x); h.y = f2bf(c.y); h.z = f2bf(c.z); h.w = f2bf(c.w);
    ((ushort4*)cbb)[(size_t)code * 64 + lane] = h;
    float ss = c.x*c.x + c.y*c.y + c.z*c.z + c.w*c.w;
    #pragma unroll
    for (int m = 32; m >= 1; m >>= 1) ss += __shfl_xor(ss, m, 64);
    if (lane == 0) hn2[code] = 0.5f * ss - 2.0f;
}

// ---------------------------------------------------------------------------
// K1: z_pre = x @ W_down.
// 128x128 block tile, 256 threads, 8x8 per thread (halves LDS reads/FLOP vs
// 8x4). Double-buffered async global->LDS DMA (global_load_lds width 16):
// one barrier per k-tile; next tile's DMA is in flight during compute.
// A XOR-swizzle is baked into the DMA *source* address (LDS dest must be
// lane-contiguous). fp32 two-level accumulation (facc/k-tile -> acc fold):
// score-space error ~1e-8 << 4.7e-7 min top-2 gap.
// ---------------------------------------------------------------------------
__global__ __launch_bounds__(256, 2) void k1_gemm1(const float4* __restrict__ X,
                                                   const float4* __restrict__ W,
                                                   float4* __restrict__ Zp) {
    __shared__ float4 Abuf[2][1024];  // 128 rows x 8 f4 (32 k), swizzled, x2
    __shared__ float4 Bbuf[2][1024];  // 32 k x 32 f4 (128 cols), natural, x2

    int tid  = threadIdx.x;
    int wid  = tid >> 6, lane = tid & 63;
    int tg   = ((wid & 1) << 3) | (lane & 7);    // row-group 0..15 (8 rows)
    int cg   = ((wid >> 1) << 3) | (lane >> 3);  // col-group 0..15 (8 cols)
    int mb   = blockIdx.x >> 1, nb = blockIdx.x & 1;
    int m0   = mb * 128;

    auto dma_tile = [&](int kt, int buf) {
        #pragma unroll
        for (int jj = 0; jj < 4; ++jj) {
            int v = jj * 256 + wid * 64 + lane;            // A slot for this lane
            int row = v >> 3;
            int kv4 = (v & 7) ^ ((row >> 3) & 7);          // inverse swizzle on source
            const float4* gp = &X[(size_t)(m0 + row) * X_F4 + kt * 8 + kv4];
            __builtin_amdgcn_global_load_lds(
                (const GLOBAL_AS uint32_t*)gp,
                (LDS_AS uint32_t*)&Abuf[buf][jj * 256 + wid * 64], 16, 0, 0);
        }
        #pragma unroll
        for (int jj = 0; jj < 4; ++jj) {
            int v = jj * 256 + wid * 64 + lane;            // B slot
            int kk = v >> 5, cv4 = v & 31;
            const float4* gp = &W[(size_t)(kk)*W_F4 + nb * 32 + cv4];  // k row set below
            gp += (size_t)kt * 32 * W_F4;
            __builtin_amdgcn_global_load_lds(
                (const GLOBAL_AS uint32_t*)gp,
                (LDS_AS uint32_t*)&Bbuf[buf][jj * 256 + wid * 64], 16, 0, 0);
        }
    };

    float acc[8][8];
    #pragma unroll
    for (int i = 0; i < 8; ++i)
        #pragma unroll
        for (int j = 0; j < 8; ++j) acc[i][j] = 0.0f;

    dma_tile(0, 0);

    for (int kt = 0; kt < 32; ++kt) {
        __syncthreads();                      // drains this tile's DMA (vmcnt)
        if (kt < 31) dma_tile(kt + 1, (kt + 1) & 1);

        const float4* As = Abuf[kt & 1];
        const float4* Bs = Bbuf[kt & 1];

        float facc[8][8];
        #pragma unroll
        for (int i = 0; i < 8; ++i)
            #pragma unroll
            for (int j = 0; j < 8; ++j) facc[i][j] = 0.0f;

        #pragma unroll
        for (int q = 0; q < 8; ++q) {
            float4 a[8], b0[4], b1[4];
            #pragma unroll
            for (int i = 0; i < 8; ++i)
                a[i] = As[(tg * 8 + i) * 8 + (q ^ (tg & 7))];
            #pragma unroll
            for (int p = 0; p < 4; ++p) {
                b0[p] = Bs[(q * 4 + p) * 32 + cg * 2];
                b1[p] = Bs[(q * 4 + p) * 32 + cg * 2 + 1];
            }
            #pragma unroll
            for (int i = 0; i < 8; ++i) {
                facc[i][0] += a[i].x*b0[0].x + a[i].y*b0[1].x + a[i].z*b0[2].x + a[i].w*b0[3].x;
                facc[i][1] += a[i].x*b0[0].y + a[i].y*b0[1].y + a[i].z*b0[2].y + a[i].w*b0[3].y;
                facc[i][2] += a[i].x*b0[0].z + a[i].y*b0[1].z + a[i].z*b0[2].z + a[i].w*b0[3].z;
                facc[i][3] += a[i].x*b0[0].w + a[i].y*b0[1].w + a[i].z*b0[2].w + a[i].w*b0[3].w;
                facc[i][4] += a[i].x*b1[0].x + a[i].y*b1[1].x + a[i].z*b1[2].x + a[i].w*b1[3].x;
                facc[i][5] += a[i].x*b1[0].y + a[i].y*b1[1].y + a[i].z*b1[2].y + a[i].w*b1[3].y;
                facc[i][6] += a[i].x*b1[0].z + a[i].y*b1[1].z + a[i].z*b1[2].z + a[i].w*b1[3].z;
                facc[i][7] += a[i].x*b1[0].w + a[i].y*b1[1].w + a[i].z*b1[2].w + a[i].w*b1[3].w;
            }
        }
        #pragma unroll
        for (int i = 0; i < 8; ++i)
            #pragma unroll
            for (int j = 0; j < 8; ++j) acc[i][j] += facc[i][j];
    }

    #pragma unroll
    for (int i = 0; i < 8; ++i) {
        int row = m0 + tg * 8 + i;
        float4 o0, o1;
        o0.x = acc[i][0]; o0.y = acc[i][1]; o0.z = acc[i][2]; o0.w = acc[i][3];
        o1.x = acc[i][4]; o1.y = acc[i][5]; o1.z = acc[i][6]; o1.w = acc[i][7];
        Zp[(size_t)row * Z_F4 + nb * 32 + cg * 2]     = o0;
        Zp[(size_t)row * Z_F4 + nb * 32 + cg * 2 + 1] = o1;
    }
}

// ---------------------------------------------------------------------------
// K1b: z = (z_pre + b) / (||z_pre + b|| + 1e-6) (unchanged)
// ---------------------------------------------------------------------------
__global__ __launch_bounds__(256) void k1b_norm(float4* __restrict__ Z,
                                                const float4* __restrict__ bias) {
    int wid = threadIdx.x >> 6, lane = threadIdx.x & 63;
    int t = blockIdx.x * 4 + wid;
    float4 b = bias[lane];
    float4 z = Z[(size_t)t * Z_F4 + lane];
    z.x += b.x; z.y += b.y; z.z += b.z; z.w += b.w;
    double ss = (double)z.x*z.x + (double)z.y*z.y + (double)z.z*z.z + (double)z.w*z.w;
    #pragma unroll
    for (int m = 32; m >= 1; m >>= 1) ss += __shfl_xor(ss, m, 64);
    float inv = 1.0f / ((float)sqrt(ss) + 1e-6f);
    z.x *= inv; z.y *= inv; z.z *= inv; z.w *= inv;
    Z[(size_t)t * Z_F4 + lane] = z;
}

// ---------------------------------------------------------------------------
// K2: bf16 MFMA candidate scoring (unchanged from round 2 — proven).
// ---------------------------------------------------------------------------
__global__ __launch_bounds__(256, 2) void k2_mfma(const float* __restrict__ Z,
                                                  const ushort* __restrict__ Cbb,
                                                  const float* __restrict__ hn2g,
                                                  int4* __restrict__ cands) {
    __shared__ __align__(16) char lds[32768 + 256];

    int tid  = threadIdx.x;
    int w    = tid >> 6;
    int lane = tid & 63;
    int c    = lane & 15, q = lane >> 4;
    int t0   = blockIdx.x * 64;

    bf16x8 A[4][8];
    #pragma unroll
    for (int mi = 0; mi < 4; ++mi) {
        #pragma unroll
        for (int ks = 0; ks < 8; ++ks) {
            const float* zp = Z + (size_t)(t0 + mi * 16 + c) * CD + ks * 32 + q * 8;
            float4 f0 = *(const float4*)zp;
            float4 f1 = *(const float4*)(zp + 4);
            bf16x8 a;
            a[0] = (short)f2bf(f0.x); a[1] = (short)f2bf(f0.y);
            a[2] = (short)f2bf(f0.z); a[3] = (short)f2bf(f0.w);
            a[4] = (short)f2bf(f1.x); a[5] = (short)f2bf(f1.y);
            a[6] = (short)f2bf(f1.z); a[7] = (short)f2bf(f1.w);
            A[mi][ks] = a;
        }
    }

    int baddr[8];
    #pragma unroll
    for (int ks = 0; ks < 8; ++ks)
        baddr[ks] = (w * 16 + c) * 512 + ((((ks * 4 + q) ^ c)) << 4);
    int hnaddr = 32768 + (w * 16 + c) * 4;

    auto issue_loads = [&](int ct, bf16x8* g, float& hnr) {
        #pragma unroll
        for (int jj = 0; jj < 8; ++jj) {
            int v = jj * 256 + tid;
            int row = v >> 5, ch = v & 31;
            int grow = ct * 64 + row; if (grow < 1) grow = 1;
            g[jj] = *(const bf16x8*)(Cbb + (size_t)grow * CD + ch * 8);
        }
        if (tid < 64) {
            int gc = ct * 64 + tid; if (gc < 1) gc = 1;
            hnr = hn2g[gc];
        }
    };
    auto write_lds = [&](const bf16x8* g, float hnr) {
        #pragma unroll
        for (int jj = 0; jj < 8; ++jj) {
            int v = jj * 256 + tid;
            int row = v >> 5, ch = v & 31;
            *(bf16x8*)(lds + row * 512 + ((ch ^ (row & 15)) << 4)) = g[jj];
        }
        if (tid < 64) *(float*)(lds + 32768 + tid * 4) = hnr;
    };

    uint32_t K1[16], K2[16];
    #pragma unroll
    for (int i = 0; i < 16; ++i) { K1[i] = 0u; K2[i] = 0u; }

    bf16x8 g[8]; float hnr = 0.0f;
    issue_loads(0, g, hnr);
    write_lds(g, hnr);

    for (int ct = 0; ct < 64; ++ct) {
        __syncthreads();
        bf16x8 g2[8]; float hnr2 = 0.0f;
        if (ct < 63) issue_loads(ct + 1, g2, hnr2);

        floatx4 C[4];
        #pragma unroll
        for (int mi = 0; mi < 4; ++mi) C[mi] = (floatx4){0.f, 0.f, 0.f, 0.f};

        #pragma unroll
        for (int ks = 0; ks < 8; ++ks) {
            bf16x8 Bf = *(const bf16x8*)(lds + baddr[ks]);
            #pragma unroll
            for (int mi = 0; mi < 4; ++mi)
                C[mi] = __builtin_amdgcn_mfma_f32_16x16x32_bf16(A[mi][ks], Bf, C[mi], 0, 0, 0);
        }

        float hv = *(const float*)(lds + hnaddr);
        #pragma unroll
        for (int mi = 0; mi < 4; ++mi) {
            #pragma unroll
            for (int r = 0; r < 4; ++r) {
                float sp = C[mi][r] - hv;
                union { float f; uint32_t u; } uv; uv.f = sp;
                uint32_t key = (uv.u & 0xFFFFFFC0u) | (uint32_t)ct;
                int i = mi * 4 + r;
                uint32_t lo = key < K1[i] ? key : K1[i];
                K1[i] = key > K1[i] ? key : K1[i];
                K2[i] = lo > K2[i] ? lo : K2[i];
            }
        }

        __syncthreads();
        if (ct < 63) write_lds(g2, hnr2);
    }

    __syncthreads();
    uint32_t* M = (uint32_t*)lds;
    #pragma unroll
    for (int mi = 0; mi < 4; ++mi) {
        #pragma unroll
        for (int r = 0; r < 4; ++r) {
            int tok = mi * 16 + q * 4 + r;
            int base = ((tok * 4 + w) * 16 + c) * 2;
            M[base]     = K1[mi * 4 + r];
            M[base + 1] = K2[mi * 4 + r];
        }
    }
    __syncthreads();
    if (tid < 64) {
        int tok = tid;
        uint32_t bk0 = 0, bk1 = 0, bk2 = 0, bk3 = 0;
        int      bp0 = 0, bp1 = 0, bp2 = 0, bp3 = 0;
        for (int e = 0; e < 128; ++e) {
            uint32_t key = M[tok * 128 + e];
            int pos = e >> 1;
            if (key > bk0) {
                bk3 = bk2; bp3 = bp2; bk2 = bk1; bp2 = bp1;
                bk1 = bk0; bp1 = bp0; bk0 = key; bp0 = pos;
            } else if (key > bk1) {
                bk3 = bk2; bp3 = bp2; bk2 = bk1; bp2 = bp1; bk1 = key; bp1 = pos;
            } else if (key > bk2) {
                bk3 = bk2; bp3 = bp2; bk2 = key; bp2 = pos;
            } else if (key > bk3) {
                bk3 = key; bp3 = pos;
            }
        }
        int4 out;
        out.x = (int)(bk0 & 63u) * 64 + bp0;
        out.y = (int)(bk1 & 63u) * 64 + bp1;
        out.z = (int)(bk2 & 63u) * 64 + bp2;
        out.w = (int)(bk3 & 63u) * 64 + bp3;
        cands[t0 + tok] = out;
    }
}

// ---------------------------------------------------------------------------
// K3: f64 re-rank of 4 candidates (unchanged).
// ---------------------------------------------------------------------------
__global__ __launch_bounds__(256) void k3_refine(const float4* __restrict__ Z,
                                                 const float4* __restrict__ Cb,
                                                 const int4* __restrict__ cands,
                                                 float* __restrict__ idxOut,
                                                 float4* __restrict__ hardOut) {
    int wid = threadIdx.x >> 6, lane = threadIdx.x & 63;
    int t = blockIdx.x * 4 + wid;
    int4 cd = cands[t];
    int cc[4] = {cd.x, cd.y, cd.z, cd.w};
    float4 z = Z[(size_t)t * Z_F4 + lane];
    double best = -1.0e300;
    int bi = NC;
    #pragma unroll
    for (int e = 0; e < 4; ++e) {
        int idx = cc[e];
        float4 cf = Cb[(size_t)idx * C_F4 + lane];
        double dot = (double)z.x*cf.x + (double)z.y*cf.y + (double)z.z*cf.z + (double)z.w*cf.w;
        double nrm = (double)cf.x*cf.x + (double)cf.y*cf.y + (double)cf.z*cf.z + (double)cf.w*cf.w;
        #pragma unroll
        for (int m = 32; m >= 1; m >>= 1) {
            dot += __shfl_xor(dot, m, 64);
            nrm += __shfl_xor(nrm, m, 64);
        }
        double s = dot - 0.5 * nrm;
        if (idx >= 1 && (s > best || (s == best && idx < bi))) { best = s; bi = idx; }
    }
    if (lane == 0) idxOut[t] = (float)bi;
    hardOut[(size_t)t * C_F4 + lane] = Cb[(size_t)bi * C_F4 + lane];
}

// ---------------------------------------------------------------------------
extern "C" void kernel_launch(void* const* d_in, const int* in_sizes, int n_in,
                              void* d_out, int out_size, void* d_ws, size_t ws_size,
                              hipStream_t stream) {
    const float* x  = (const float*)d_in[0];   // 32768 x 1024
    const float* cb = (const float*)d_in[1];   // 4096 x 256
    const float* w  = (const float*)d_in[2];   // 1024 x 256
    const float* bd = (const float*)d_in[3];   // 256

    float* zOut    = (float*)d_out;                    // 32768 x 256
    float* idxOut  = zOut + (size_t)NT * CD;           // 32768 (as float values)
    float* hardOut = idxOut + NT;                      // 32768 x 256

    float*  hn2   = (float*)d_ws;                            // 16 KB
    int4*   cands = (int4*)((char*)d_ws + 16384);            // 512 KB
    ushort* cbb   = (ushort*)((char*)d_ws + 16384 + 524288); // 2 MB bf16 codebook

    k0_prep<<<NC / 4, 256, 0, stream>>>((const float4*)cb, hn2, cbb);
    k1_gemm1<<<(NT / 128) * (CD / 128), 256, 0, stream>>>((const float4*)x,
                                                          (const float4*)w,
                                                          (float4*)zOut);
    k1b_norm<<<NT / 4, 256, 0, stream>>>((float4*)zOut, (const float4*)bd);
    k2_mfma<<<NT / 64, 256, 0, stream>>>(zOut, cbb, hn2, cands);
    k3_refine<<<NT / 4, 256, 0, stream>>>((const float4*)zOut, (const float4*)cb,
                                          cands, idxOut, (float4*)hardOut);
}

// Round 4
// 5597.712 us; speedup vs baseline: 1.0725x; 1.0725x over previous
//
#include <hip/hip_runtime.h>
#include <math.h>
#include <stdint.h>

#define NT 32768
#define DM 1024
#define NC 4096
#define CD 256

#define X_F4 (DM/4)
#define W_F4 (CD/4)
#define Z_F4 (CD/4)
#define C_F4 (CD/4)

typedef __attribute__((ext_vector_type(8))) short bf16x8;
typedef __attribute__((ext_vector_type(4))) float floatx4;

__device__ __forceinline__ unsigned short f2bf(float f) {
    union { float f; uint32_t u; } v; v.f = f;
    uint32_t u = v.u;
    u += 0x7FFFu + ((u >> 16) & 1u);   // RN-even
    return (unsigned short)(u >> 16);
}

// ---------------------------------------------------------------------------
// K0: per-code prep: hn2[code] = 0.5*||c||^2 - 2, bf16 codebook copy.
// ---------------------------------------------------------------------------
__global__ __launch_bounds__(256) void k0_prep(const float4* __restrict__ cb,
                                               float* __restrict__ hn2,
                                               ushort* __restrict__ cbb) {
    int wid = threadIdx.x >> 6, lane = threadIdx.x & 63;
    int code = blockIdx.x * 4 + wid;
    float4 c = cb[(size_t)code * C_F4 + lane];
    ushort4 h;
    h.x = f2bf(c.x); h.y = f2bf(c.y); h.z = f2bf(c.z); h.w = f2bf(c.w);
    ((ushort4*)cbb)[(size_t)code * 64 + lane] = h;
    float ss = c.x*c.x + c.y*c.y + c.z*c.z + c.w*c.w;
    #pragma unroll
    for (int m = 32; m >= 1; m >>= 1) ss += __shfl_xor(ss, m, 64);
    if (lane == 0) hn2[code] = 0.5f * ss - 2.0f;
}

// ---------------------------------------------------------------------------
// K1: z_pre = x @ W_down.
// 128x128 block tile, 256 threads, 8x8 per thread. Round-2 codegen style
// (global->VGPR->ds_write staging; NO global_load_lds, NO lambdas — round 3's
// DMA path triggered a 128-VGPR allocation + full scratch spill of the
// accumulators: 9.7 GB WRITE_SIZE). Double-buffered LDS, ONE barrier/tile:
// tile k+1's global loads issue before compute of tile k and land during it.
// fp32 two-level accumulation (round-3-proven numerics, ~4e-7 score error).
// ---------------------------------------------------------------------------
__global__ __launch_bounds__(256, 2) void k1_gemm1(const float4* __restrict__ X,
                                                   const float4* __restrict__ W,
                                                   float4* __restrict__ Zp) {
    __shared__ float4 Abuf[2][1024];  // 128 rows x 8 f4 (32 k), swizzled
    __shared__ float4 Bbuf[2][1024];  // 32 k x 32 f4 (128 cols), natural

    int tid  = threadIdx.x;
    int wid  = tid >> 6, lane = tid & 63;
    int tg   = ((wid & 1) << 3) | (lane & 7);    // row-group 0..15 (8 rows)
    int cg   = ((wid >> 1) << 3) | (lane >> 3);  // col-group 0..15 (8 cols)
    int mb   = blockIdx.x >> 1, nb = blockIdx.x & 1;
    int m0   = mb * 128;

    // Staging slot geometry (fixed per thread)
    int av[4], arow[4], akv[4];                  // A: 4 slots
    #pragma unroll
    for (int jj = 0; jj < 4; ++jj) {
        int v = jj * 256 + tid;
        arow[jj] = v >> 3;
        akv[jj]  = v & 7;
        av[jj]   = arow[jj] * 8 + (akv[jj] ^ ((arow[jj] >> 3) & 7));
    }
    int bkk[4], bcv[4];                          // B: 4 slots
    #pragma unroll
    for (int jj = 0; jj < 4; ++jj) {
        int v = jj * 256 + tid;
        bkk[jj] = v >> 5;
        bcv[jj] = v & 31;
    }

    float acc[8][8];
    #pragma unroll
    for (int i = 0; i < 8; ++i)
        #pragma unroll
        for (int j = 0; j < 8; ++j) acc[i][j] = 0.0f;

    // Preload tile 0 into staging VGPRs
    float4 ga[4], gb[4];
    #pragma unroll
    for (int jj = 0; jj < 4; ++jj) {
        ga[jj] = X[(size_t)(m0 + arow[jj]) * X_F4 + 0 * 8 + akv[jj]];
        gb[jj] = W[(size_t)(0 * 32 + bkk[jj]) * W_F4 + nb * 32 + bcv[jj]];
    }

    for (int kt = 0; kt < 32; ++kt) {
        float4* As = Abuf[kt & 1];
        float4* Bs = Bbuf[kt & 1];

        // Commit staged tile kt to LDS
        #pragma unroll
        for (int jj = 0; jj < 4; ++jj) {
            As[av[jj]] = ga[jj];
            Bs[bkk[jj] * 32 + bcv[jj]] = gb[jj];
        }

        // Issue tile kt+1 global loads (land during compute below)
        if (kt < 31) {
            #pragma unroll
            for (int jj = 0; jj < 4; ++jj) {
                ga[jj] = X[(size_t)(m0 + arow[jj]) * X_F4 + (kt + 1) * 8 + akv[jj]];
                gb[jj] = W[(size_t)((kt + 1) * 32 + bkk[jj]) * W_F4 + nb * 32 + bcv[jj]];
            }
        }

        __syncthreads();   // writes to buf[kt&1] visible; protects vs tile kt-1 readers

        float facc[8][8];
        #pragma unroll
        for (int i = 0; i < 8; ++i)
            #pragma unroll
            for (int j = 0; j < 8; ++j) facc[i][j] = 0.0f;

        #pragma unroll
        for (int q = 0; q < 8; ++q) {
            float4 a[8];
            #pragma unroll
            for (int i = 0; i < 8; ++i)
                a[i] = As[(tg * 8 + i) * 8 + (q ^ (tg & 7))];
            float4 b[4];
            #pragma unroll
            for (int p = 0; p < 4; ++p)
                b[p] = Bs[(q * 4 + p) * 32 + cg * 2];
            #pragma unroll
            for (int i = 0; i < 8; ++i) {
                facc[i][0] += a[i].x*b[0].x + a[i].y*b[1].x + a[i].z*b[2].x + a[i].w*b[3].x;
                facc[i][1] += a[i].x*b[0].y + a[i].y*b[1].y + a[i].z*b[2].y + a[i].w*b[3].y;
                facc[i][2] += a[i].x*b[0].z + a[i].y*b[1].z + a[i].z*b[2].z + a[i].w*b[3].z;
                facc[i][3] += a[i].x*b[0].w + a[i].y*b[1].w + a[i].z*b[2].w + a[i].w*b[3].w;
            }
            #pragma unroll
            for (int p = 0; p < 4; ++p)
                b[p] = Bs[(q * 4 + p) * 32 + cg * 2 + 1];
            #pragma unroll
            for (int i = 0; i < 8; ++i) {
                facc[i][4] += a[i].x*b[0].x + a[i].y*b[1].x + a[i].z*b[2].x + a[i].w*b[3].x;
                facc[i][5] += a[i].x*b[0].y + a[i].y*b[1].y + a[i].z*b[2].y + a[i].w*b[3].y;
                facc[i][6] += a[i].x*b[0].z + a[i].y*b[1].z + a[i].z*b[2].z + a[i].w*b[3].z;
                facc[i][7] += a[i].x*b[0].w + a[i].y*b[1].w + a[i].z*b[2].w + a[i].w*b[3].w;
            }
        }
        #pragma unroll
        for (int i = 0; i < 8; ++i)
            #pragma unroll
            for (int j = 0; j < 8; ++j) acc[i][j] += facc[i][j];

        __syncthreads();   // compute done before next tile overwrites buf[(kt+1)&1]? no:
                           // next writes hit the OTHER buffer; this barrier instead keeps
                           // tile kt+2's writes (same buffer) behind everyone's kt reads.
    }

    #pragma unroll
    for (int i = 0; i < 8; ++i) {
        int row = m0 + tg * 8 + i;
        float4 o0, o1;
        o0.x = acc[i][0]; o0.y = acc[i][1]; o0.z = acc[i][2]; o0.w = acc[i][3];
        o1.x = acc[i][4]; o1.y = acc[i][5]; o1.z = acc[i][6]; o1.w = acc[i][7];
        Zp[(size_t)row * Z_F4 + nb * 32 + cg * 2]     = o0;
        Zp[(size_t)row * Z_F4 + nb * 32 + cg * 2 + 1] = o1;
    }
}

// ---------------------------------------------------------------------------
// K1b: z = (z_pre + b) / (||z_pre + b|| + 1e-6) (unchanged)
// ---------------------------------------------------------------------------
__global__ __launch_bounds__(256) void k1b_norm(float4* __restrict__ Z,
                                                const float4* __restrict__ bias) {
    int wid = threadIdx.x >> 6, lane = threadIdx.x & 63;
    int t = blockIdx.x * 4 + wid;
    float4 b = bias[lane];
    float4 z = Z[(size_t)t * Z_F4 + lane];
    z.x += b.x; z.y += b.y; z.z += b.z; z.w += b.w;
    double ss = (double)z.x*z.x + (double)z.y*z.y + (double)z.z*z.z + (double)z.w*z.w;
    #pragma unroll
    for (int m = 32; m >= 1; m >>= 1) ss += __shfl_xor(ss, m, 64);
    float inv = 1.0f / ((float)sqrt(ss) + 1e-6f);
    z.x *= inv; z.y *= inv; z.z *= inv; z.w *= inv;
    Z[(size_t)t * Z_F4 + lane] = z;
}

// ---------------------------------------------------------------------------
// K2: bf16 MFMA candidate scoring (unchanged — proven).
// ---------------------------------------------------------------------------
__global__ __launch_bounds__(256, 2) void k2_mfma(const float* __restrict__ Z,
                                                  const ushort* __restrict__ Cbb,
                                                  const float* __restrict__ hn2g,
                                                  int4* __restrict__ cands) {
    __shared__ __align__(16) char lds[32768 + 256];

    int tid  = threadIdx.x;
    int w    = tid >> 6;
    int lane = tid & 63;
    int c    = lane & 15, q = lane >> 4;
    int t0   = blockIdx.x * 64;

    bf16x8 A[4][8];
    #pragma unroll
    for (int mi = 0; mi < 4; ++mi) {
        #pragma unroll
        for (int ks = 0; ks < 8; ++ks) {
            const float* zp = Z + (size_t)(t0 + mi * 16 + c) * CD + ks * 32 + q * 8;
            float4 f0 = *(const float4*)zp;
            float4 f1 = *(const float4*)(zp + 4);
            bf16x8 a;
            a[0] = (short)f2bf(f0.x); a[1] = (short)f2bf(f0.y);
            a[2] = (short)f2bf(f0.z); a[3] = (short)f2bf(f0.w);
            a[4] = (short)f2bf(f1.x); a[5] = (short)f2bf(f1.y);
            a[6] = (short)f2bf(f1.z); a[7] = (short)f2bf(f1.w);
            A[mi][ks] = a;
        }
    }

    int baddr[8];
    #pragma unroll
    for (int ks = 0; ks < 8; ++ks)
        baddr[ks] = (w * 16 + c) * 512 + ((((ks * 4 + q) ^ c)) << 4);
    int hnaddr = 32768 + (w * 16 + c) * 4;

    auto issue_loads = [&](int ct, bf16x8* g, float& hnr) {
        #pragma unroll
        for (int jj = 0; jj < 8; ++jj) {
            int v = jj * 256 + tid;
            int row = v >> 5, ch = v & 31;
            int grow = ct * 64 + row; if (grow < 1) grow = 1;
            g[jj] = *(const bf16x8*)(Cbb + (size_t)grow * CD + ch * 8);
        }
        if (tid < 64) {
            int gc = ct * 64 + tid; if (gc < 1) gc = 1;
            hnr = hn2g[gc];
        }
    };
    auto write_lds = [&](const bf16x8* g, float hnr) {
        #pragma unroll
        for (int jj = 0; jj < 8; ++jj) {
            int v = jj * 256 + tid;
            int row = v >> 5, ch = v & 31;
            *(bf16x8*)(lds + row * 512 + ((ch ^ (row & 15)) << 4)) = g[jj];
        }
        if (tid < 64) *(float*)(lds + 32768 + tid * 4) = hnr;
    };

    uint32_t K1[16], K2[16];
    #pragma unroll
    for (int i = 0; i < 16; ++i) { K1[i] = 0u; K2[i] = 0u; }

    bf16x8 g[8]; float hnr = 0.0f;
    issue_loads(0, g, hnr);
    write_lds(g, hnr);

    for (int ct = 0; ct < 64; ++ct) {
        __syncthreads();
        bf16x8 g2[8]; float hnr2 = 0.0f;
        if (ct < 63) issue_loads(ct + 1, g2, hnr2);

        floatx4 C[4];
        #pragma unroll
        for (int mi = 0; mi < 4; ++mi) C[mi] = (floatx4){0.f, 0.f, 0.f, 0.f};

        #pragma unroll
        for (int ks = 0; ks < 8; ++ks) {
            bf16x8 Bf = *(const bf16x8*)(lds + baddr[ks]);
            #pragma unroll
            for (int mi = 0; mi < 4; ++mi)
                C[mi] = __builtin_amdgcn_mfma_f32_16x16x32_bf16(A[mi][ks], Bf, C[mi], 0, 0, 0);
        }

        float hv = *(const float*)(lds + hnaddr);
        #pragma unroll
        for (int mi = 0; mi < 4; ++mi) {
            #pragma unroll
            for (int r = 0; r < 4; ++r) {
                float sp = C[mi][r] - hv;
                union { float f; uint32_t u; } uv; uv.f = sp;
                uint32_t key = (uv.u & 0xFFFFFFC0u) | (uint32_t)ct;
                int i = mi * 4 + r;
                uint32_t lo = key < K1[i] ? key : K1[i];
                K1[i] = key > K1[i] ? key : K1[i];
                K2[i] = lo > K2[i] ? lo : K2[i];
            }
        }

        __syncthreads();
        if (ct < 63) write_lds(g2, hnr2);
    }

    __syncthreads();
    uint32_t* M = (uint32_t*)lds;
    #pragma unroll
    for (int mi = 0; mi < 4; ++mi) {
        #pragma unroll
        for (int r = 0; r < 4; ++r) {
            int tok = mi * 16 + q * 4 + r;
            int base = ((tok * 4 + w) * 16 + c) * 2;
            M[base]     = K1[mi * 4 + r];
            M[base + 1] = K2[mi * 4 + r];
        }
    }
    __syncthreads();
    if (tid < 64) {
        int tok = tid;
        uint32_t bk0 = 0, bk1 = 0, bk2 = 0, bk3 = 0;
        int      bp0 = 0, bp1 = 0, bp2 = 0, bp3 = 0;
        for (int e = 0; e < 128; ++e) {
            uint32_t key = M[tok * 128 + e];
            int pos = e >> 1;
            if (key > bk0) {
                bk3 = bk2; bp3 = bp2; bk2 = bk1; bp2 = bp1;
                bk1 = bk0; bp1 = bp0; bk0 = key; bp0 = pos;
            } else if (key > bk1) {
                bk3 = bk2; bp3 = bp2; bk2 = bk1; bp2 = bp1; bk1 = key; bp1 = pos;
            } else if (key > bk2) {
                bk3 = bk2; bp3 = bp2; bk2 = key; bp2 = pos;
            } else if (key > bk3) {
                bk3 = key; bp3 = pos;
            }
        }
        int4 out;
        out.x = (int)(bk0 & 63u) * 64 + bp0;
        out.y = (int)(bk1 & 63u) * 64 + bp1;
        out.z = (int)(bk2 & 63u) * 64 + bp2;
        out.w = (int)(bk3 & 63u) * 64 + bp3;
        cands[t0 + tok] = out;
    }
}

// ---------------------------------------------------------------------------
// K3: f64 re-rank of 4 candidates (unchanged).
// ---------------------------------------------------------------------------
__global__ __launch_bounds__(256) void k3_refine(const float4* __restrict__ Z,
                                                 const float4* __restrict__ Cb,
                                                 const int4* __restrict__ cands,
                                                 float* __restrict__ idxOut,
                                                 float4* __restrict__ hardOut) {
    int wid = threadIdx.x >> 6, lane = threadIdx.x & 63;
    int t = blockIdx.x * 4 + wid;
    int4 cd = cands[t];
    int cc[4] = {cd.x, cd.y, cd.z, cd.w};
    float4 z = Z[(size_t)t * Z_F4 + lane];
    double best = -1.0e300;
    int bi = NC;
    #pragma unroll
    for (int e = 0; e < 4; ++e) {
        int idx = cc[e];
        float4 cf = Cb[(size_t)idx * C_F4 + lane];
        double dot = (double)z.x*cf.x + (double)z.y*cf.y + (double)z.z*cf.z + (double)z.w*cf.w;
        double nrm = (double)cf.x*cf.x + (double)cf.y*cf.y + (double)cf.z*cf.z + (double)cf.w*cf.w;
        #pragma unroll
        for (int m = 32; m >= 1; m >>= 1) {
            dot += __shfl_xor(dot, m, 64);
            nrm += __shfl_xor(nrm, m, 64);
        }
        double s = dot - 0.5 * nrm;
        if (idx >= 1 && (s > best || (s == best && idx < bi))) { best = s; bi = idx; }
    }
    if (lane == 0) idxOut[t] = (float)bi;
    hardOut[(size_t)t * C_F4 + lane] = Cb[(size_t)bi * C_F4 + lane];
}

// ---------------------------------------------------------------------------
extern "C" void kernel_launch(void* const* d_in, const int* in_sizes, int n_in,
                              void* d_out, int out_size, void* d_ws, size_t ws_size,
                              hipStream_t stream) {
    const float* x  = (const float*)d_in[0];   // 32768 x 1024
    const float* cb = (const float*)d_in[1];   // 4096 x 256
    const float* w  = (const float*)d_in[2];   // 1024 x 256
    const float* bd = (const float*)d_in[3];   // 256

    float* zOut    = (float*)d_out;                    // 32768 x 256
    float* idxOut  = zOut + (size_t)NT * CD;           // 32768 (as float values)
    float* hardOut = idxOut + NT;                      // 32768 x 256

    float*  hn2   = (float*)d_ws;                            // 16 KB
    int4*   cands = (int4*)((char*)d_ws + 16384);            // 512 KB
    ushort* cbb   = (ushort*)((char*)d_ws + 16384 + 524288); // 2 MB bf16 codebook

    k0_prep<<<NC / 4, 256, 0, stream>>>((const float4*)cb, hn2, cbb);
    k1_gemm1<<<(NT / 128) * (CD / 128), 256, 0, stream>>>((const float4*)x,
                                                          (const float4*)w,
                                                          (float4*)zOut);
    k1b_norm<<<NT / 4, 256, 0, stream>>>((float4*)zOut, (const float4*)bd);
    k2_mfma<<<NT / 64, 256, 0, stream>>>(zOut, cbb, hn2, cands);
    k3_refine<<<NT / 4, 256, 0, stream>>>((const float4*)zOut, (const float4*)cb,
                                          cands, idxOut, (float4*)hardOut);
}

// Round 5
// 2714.110 us; speedup vs baseline: 2.2121x; 2.0624x over previous
//
#include <hip/hip_runtime.h>
#include <math.h>
#include <stdint.h>

#define NT 32768
#define DM 1024
#define NC 4096
#define CD 256

#define X_F4 (DM/4)
#define W_F4 (CD/4)
#define Z_F4 (CD/4)
#define C_F4 (CD/4)

typedef __attribute__((ext_vector_type(8))) short bf16x8;
typedef __attribute__((ext_vector_type(4))) float floatx4;

__device__ __forceinline__ unsigned short f2bf(float f) {
    union { float f; uint32_t u; } v; v.f = f;
    uint32_t u = v.u;
    u += 0x7FFFu + ((u >> 16) & 1u);   // RN-even
    return (unsigned short)(u >> 16);
}

// ---------------------------------------------------------------------------
// K0: per-code prep: hn2[code] = 0.5*||c||^2 - 2, bf16 codebook copy.
// ---------------------------------------------------------------------------
__global__ __launch_bounds__(256) void k0_prep(const float4* __restrict__ cb,
                                               float* __restrict__ hn2,
                                               ushort* __restrict__ cbb) {
    int wid = threadIdx.x >> 6, lane = threadIdx.x & 63;
    int code = blockIdx.x * 4 + wid;
    float4 c = cb[(size_t)code * C_F4 + lane];
    ushort4 h;
    h.x = f2bf(c.x); h.y = f2bf(c.y); h.z = f2bf(c.z); h.w = f2bf(c.w);
    ((ushort4*)cbb)[(size_t)code * 64 + lane] = h;
    float ss = c.x*c.x + c.y*c.y + c.z*c.z + c.w*c.w;
    #pragma unroll
    for (int m = 32; m >= 1; m >>= 1) ss += __shfl_xor(ss, m, 64);
    if (lane == 0) hn2[code] = 0.5f * ss - 2.0f;
}

// ---------------------------------------------------------------------------
// K1: z_pre = x @ W_down.
// 128x128 block tile, 256 threads, 8x8 per thread. PLAIN __launch_bounds__
// (256): on this toolchain `__launch_bounds__(256, 2)` hard-caps arch VGPRs
// at 128 (rounds 3/4: 10 GB scratch-spill traffic); plain bounds let the
// allocator take ~230 regs (round 1/2 evidence: 196-256 allocated cleanly).
// Double-buffered LDS; tile k+1's global loads issue before compute of tile
// k. fp32 two-level accumulation (proven passing, rounds 3-4).
// ---------------------------------------------------------------------------
__global__ __launch_bounds__(256) void k1_gemm1(const float4* __restrict__ X,
                                                const float4* __restrict__ W,
                                                float4* __restrict__ Zp) {
    __shared__ float4 Abuf[2][1024];  // 128 rows x 8 f4 (32 k), swizzled
    __shared__ float4 Bbuf[2][1024];  // 32 k x 32 f4 (128 cols), natural

    int tid  = threadIdx.x;
    int wid  = tid >> 6, lane = tid & 63;
    int tg   = ((wid & 1) << 3) | (lane & 7);    // row-group 0..15 (8 rows)
    int cg   = ((wid >> 1) << 3) | (lane >> 3);  // col-group 0..15 (8 cols)
    int mb   = blockIdx.x >> 1, nb = blockIdx.x & 1;
    int m0   = mb * 128;

    int av[4], arow[4], akv[4];                  // A staging slots
    #pragma unroll
    for (int jj = 0; jj < 4; ++jj) {
        int v = jj * 256 + tid;
        arow[jj] = v >> 3;
        akv[jj]  = v & 7;
        av[jj]   = arow[jj] * 8 + (akv[jj] ^ ((arow[jj] >> 3) & 7));
    }
    int bkk[4], bcv[4];                          // B staging slots
    #pragma unroll
    for (int jj = 0; jj < 4; ++jj) {
        int v = jj * 256 + tid;
        bkk[jj] = v >> 5;
        bcv[jj] = v & 31;
    }

    float acc[8][8];
    #pragma unroll
    for (int i = 0; i < 8; ++i)
        #pragma unroll
        for (int j = 0; j < 8; ++j) acc[i][j] = 0.0f;

    float4 ga[4], gb[4];
    #pragma unroll
    for (int jj = 0; jj < 4; ++jj) {
        ga[jj] = X[(size_t)(m0 + arow[jj]) * X_F4 + 0 * 8 + akv[jj]];
        gb[jj] = W[(size_t)(0 * 32 + bkk[jj]) * W_F4 + nb * 32 + bcv[jj]];
    }

    for (int kt = 0; kt < 32; ++kt) {
        float4* As = Abuf[kt & 1];
        float4* Bs = Bbuf[kt & 1];

        #pragma unroll
        for (int jj = 0; jj < 4; ++jj) {
            As[av[jj]] = ga[jj];
            Bs[bkk[jj] * 32 + bcv[jj]] = gb[jj];
        }

        if (kt < 31) {
            #pragma unroll
            for (int jj = 0; jj < 4; ++jj) {
                ga[jj] = X[(size_t)(m0 + arow[jj]) * X_F4 + (kt + 1) * 8 + akv[jj]];
                gb[jj] = W[(size_t)((kt + 1) * 32 + bkk[jj]) * W_F4 + nb * 32 + bcv[jj]];
            }
        }

        __syncthreads();

        float facc[8][8];
        #pragma unroll
        for (int i = 0; i < 8; ++i)
            #pragma unroll
            for (int j = 0; j < 8; ++j) facc[i][j] = 0.0f;

        #pragma unroll
        for (int q = 0; q < 8; ++q) {
            float4 a[8];
            #pragma unroll
            for (int i = 0; i < 8; ++i)
                a[i] = As[(tg * 8 + i) * 8 + (q ^ (tg & 7))];
            float4 b[4];
            #pragma unroll
            for (int p = 0; p < 4; ++p)
                b[p] = Bs[(q * 4 + p) * 32 + cg * 2];
            #pragma unroll
            for (int i = 0; i < 8; ++i) {
                facc[i][0] += a[i].x*b[0].x + a[i].y*b[1].x + a[i].z*b[2].x + a[i].w*b[3].x;
                facc[i][1] += a[i].x*b[0].y + a[i].y*b[1].y + a[i].z*b[2].y + a[i].w*b[3].y;
                facc[i][2] += a[i].x*b[0].z + a[i].y*b[1].z + a[i].z*b[2].z + a[i].w*b[3].z;
                facc[i][3] += a[i].x*b[0].w + a[i].y*b[1].w + a[i].z*b[2].w + a[i].w*b[3].w;
            }
            #pragma unroll
            for (int p = 0; p < 4; ++p)
                b[p] = Bs[(q * 4 + p) * 32 + cg * 2 + 1];
            #pragma unroll
            for (int i = 0; i < 8; ++i) {
                facc[i][4] += a[i].x*b[0].x + a[i].y*b[1].x + a[i].z*b[2].x + a[i].w*b[3].x;
                facc[i][5] += a[i].x*b[0].y + a[i].y*b[1].y + a[i].z*b[2].y + a[i].w*b[3].y;
                facc[i][6] += a[i].x*b[0].z + a[i].y*b[1].z + a[i].z*b[2].z + a[i].w*b[3].z;
                facc[i][7] += a[i].x*b[0].w + a[i].y*b[1].w + a[i].z*b[2].w + a[i].w*b[3].w;
            }
        }
        #pragma unroll
        for (int i = 0; i < 8; ++i)
            #pragma unroll
            for (int j = 0; j < 8; ++j) acc[i][j] += facc[i][j];

        __syncthreads();
    }

    #pragma unroll
    for (int i = 0; i < 8; ++i) {
        int row = m0 + tg * 8 + i;
        float4 o0, o1;
        o0.x = acc[i][0]; o0.y = acc[i][1]; o0.z = acc[i][2]; o0.w = acc[i][3];
        o1.x = acc[i][4]; o1.y = acc[i][5]; o1.z = acc[i][6]; o1.w = acc[i][7];
        Zp[(size_t)row * Z_F4 + nb * 32 + cg * 2]     = o0;
        Zp[(size_t)row * Z_F4 + nb * 32 + cg * 2 + 1] = o1;
    }
}

// ---------------------------------------------------------------------------
// K1b: z = (z_pre + b) / (||z_pre + b|| + 1e-6) (unchanged)
// ---------------------------------------------------------------------------
__global__ __launch_bounds__(256) void k1b_norm(float4* __restrict__ Z,
                                                const float4* __restrict__ bias) {
    int wid = threadIdx.x >> 6, lane = threadIdx.x & 63;
    int t = blockIdx.x * 4 + wid;
    float4 b = bias[lane];
    float4 z = Z[(size_t)t * Z_F4 + lane];
    z.x += b.x; z.y += b.y; z.z += b.z; z.w += b.w;
    double ss = (double)z.x*z.x + (double)z.y*z.y + (double)z.z*z.z + (double)z.w*z.w;
    #pragma unroll
    for (int m = 32; m >= 1; m >>= 1) ss += __shfl_xor(ss, m, 64);
    float inv = 1.0f / ((float)sqrt(ss) + 1e-6f);
    z.x *= inv; z.y *= inv; z.z *= inv; z.w *= inv;
    Z[(size_t)t * Z_F4 + lane] = z;
}

// ---------------------------------------------------------------------------
// K2: bf16 MFMA candidate scoring. Plain __launch_bounds__(256) — the (,2)
// variant risks the same 128-VGPR cap (A frags alone are 128 VGPRs).
// ---------------------------------------------------------------------------
__global__ __launch_bounds__(256) void k2_mfma(const float* __restrict__ Z,
                                               const ushort* __restrict__ Cbb,
                                               const float* __restrict__ hn2g,
                                               int4* __restrict__ cands) {
    __shared__ __align__(16) char lds[32768 + 256];

    int tid  = threadIdx.x;
    int w    = tid >> 6;
    int lane = tid & 63;
    int c    = lane & 15, q = lane >> 4;
    int t0   = blockIdx.x * 64;

    bf16x8 A[4][8];
    #pragma unroll
    for (int mi = 0; mi < 4; ++mi) {
        #pragma unroll
        for (int ks = 0; ks < 8; ++ks) {
            const float* zp = Z + (size_t)(t0 + mi * 16 + c) * CD + ks * 32 + q * 8;
            float4 f0 = *(const float4*)zp;
            float4 f1 = *(const float4*)(zp + 4);
            bf16x8 a;
            a[0] = (short)f2bf(f0.x); a[1] = (short)f2bf(f0.y);
            a[2] = (short)f2bf(f0.z); a[3] = (short)f2bf(f0.w);
            a[4] = (short)f2bf(f1.x); a[5] = (short)f2bf(f1.y);
            a[6] = (short)f2bf(f1.z); a[7] = (short)f2bf(f1.w);
            A[mi][ks] = a;
        }
    }

    int baddr[8];
    #pragma unroll
    for (int ks = 0; ks < 8; ++ks)
        baddr[ks] = (w * 16 + c) * 512 + ((((ks * 4 + q) ^ c)) << 4);
    int hnaddr = 32768 + (w * 16 + c) * 4;

    auto issue_loads = [&](int ct, bf16x8* g, float& hnr) {
        #pragma unroll
        for (int jj = 0; jj < 8; ++jj) {
            int v = jj * 256 + tid;
            int row = v >> 5, ch = v & 31;
            int grow = ct * 64 + row; if (grow < 1) grow = 1;
            g[jj] = *(const bf16x8*)(Cbb + (size_t)grow * CD + ch * 8);
        }
        if (tid < 64) {
            int gc = ct * 64 + tid; if (gc < 1) gc = 1;
            hnr = hn2g[gc];
        }
    };
    auto write_lds = [&](const bf16x8* g, float hnr) {
        #pragma unroll
        for (int jj = 0; jj < 8; ++jj) {
            int v = jj * 256 + tid;
            int row = v >> 5, ch = v & 31;
            *(bf16x8*)(lds + row * 512 + ((ch ^ (row & 15)) << 4)) = g[jj];
        }
        if (tid < 64) *(float*)(lds + 32768 + tid * 4) = hnr;
    };

    uint32_t K1[16], K2[16];
    #pragma unroll
    for (int i = 0; i < 16; ++i) { K1[i] = 0u; K2[i] = 0u; }

    bf16x8 g[8]; float hnr = 0.0f;
    issue_loads(0, g, hnr);
    write_lds(g, hnr);

    for (int ct = 0; ct < 64; ++ct) {
        __syncthreads();
        bf16x8 g2[8]; float hnr2 = 0.0f;
        if (ct < 63) issue_loads(ct + 1, g2, hnr2);

        floatx4 C[4];
        #pragma unroll
        for (int mi = 0; mi < 4; ++mi) C[mi] = (floatx4){0.f, 0.f, 0.f, 0.f};

        #pragma unroll
        for (int ks = 0; ks < 8; ++ks) {
            bf16x8 Bf = *(const bf16x8*)(lds + baddr[ks]);
            #pragma unroll
            for (int mi = 0; mi < 4; ++mi)
                C[mi] = __builtin_amdgcn_mfma_f32_16x16x32_bf16(A[mi][ks], Bf, C[mi], 0, 0, 0);
        }

        float hv = *(const float*)(lds + hnaddr);
        #pragma unroll
        for (int mi = 0; mi < 4; ++mi) {
            #pragma unroll
            for (int r = 0; r < 4; ++r) {
                float sp = C[mi][r] - hv;
                union { float f; uint32_t u; } uv; uv.f = sp;
                uint32_t key = (uv.u & 0xFFFFFFC0u) | (uint32_t)ct;
                int i = mi * 4 + r;
                uint32_t lo = key < K1[i] ? key : K1[i];
                K1[i] = key > K1[i] ? key : K1[i];
                K2[i] = lo > K2[i] ? lo : K2[i];
            }
        }

        __syncthreads();
        if (ct < 63) write_lds(g2, hnr2);
    }

    __syncthreads();
    uint32_t* M = (uint32_t*)lds;
    #pragma unroll
    for (int mi = 0; mi < 4; ++mi) {
        #pragma unroll
        for (int r = 0; r < 4; ++r) {
            int tok = mi * 16 + q * 4 + r;
            int base = ((tok * 4 + w) * 16 + c) * 2;
            M[base]     = K1[mi * 4 + r];
            M[base + 1] = K2[mi * 4 + r];
        }
    }
    __syncthreads();
    if (tid < 64) {
        int tok = tid;
        uint32_t bk0 = 0, bk1 = 0, bk2 = 0, bk3 = 0;
        int      bp0 = 0, bp1 = 0, bp2 = 0, bp3 = 0;
        for (int e = 0; e < 128; ++e) {
            uint32_t key = M[tok * 128 + e];
            int pos = e >> 1;
            if (key > bk0) {
                bk3 = bk2; bp3 = bp2; bk2 = bk1; bp2 = bp1;
                bk1 = bk0; bp1 = bp0; bk0 = key; bp0 = pos;
            } else if (key > bk1) {
                bk3 = bk2; bp3 = bp2; bk2 = bk1; bp2 = bp1; bk1 = key; bp1 = pos;
            } else if (key > bk2) {
                bk3 = bk2; bp3 = bp2; bk2 = key; bp2 = pos;
            } else if (key > bk3) {
                bk3 = key; bp3 = pos;
            }
        }
        int4 out;
        out.x = (int)(bk0 & 63u) * 64 + bp0;
        out.y = (int)(bk1 & 63u) * 64 + bp1;
        out.z = (int)(bk2 & 63u) * 64 + bp2;
        out.w = (int)(bk3 & 63u) * 64 + bp3;
        cands[t0 + tok] = out;
    }
}

// ---------------------------------------------------------------------------
// K3: f64 re-rank of 4 candidates (unchanged).
// ---------------------------------------------------------------------------
__global__ __launch_bounds__(256) void k3_refine(const float4* __restrict__ Z,
                                                 const float4* __restrict__ Cb,
                                                 const int4* __restrict__ cands,
                                                 float* __restrict__ idxOut,
                                                 float4* __restrict__ hardOut) {
    int wid = threadIdx.x >> 6, lane = threadIdx.x & 63;
    int t = blockIdx.x * 4 + wid;
    int4 cd = cands[t];
    int cc[4] = {cd.x, cd.y, cd.z, cd.w};
    float4 z = Z[(size_t)t * Z_F4 + lane];
    double best = -1.0e300;
    int bi = NC;
    #pragma unroll
    for (int e = 0; e < 4; ++e) {
        int idx = cc[e];
        float4 cf = Cb[(size_t)idx * C_F4 + lane];
        double dot = (double)z.x*cf.x + (double)z.y*cf.y + (double)z.z*cf.z + (double)z.w*cf.w;
        double nrm = (double)cf.x*cf.x + (double)cf.y*cf.y + (double)cf.z*cf.z + (double)cf.w*cf.w;
        #pragma unroll
        for (int m = 32; m >= 1; m >>= 1) {
            dot += __shfl_xor(dot, m, 64);
            nrm += __shfl_xor(nrm, m, 64);
        }
        double s = dot - 0.5 * nrm;
        if (idx >= 1 && (s > best || (s == best && idx < bi))) { best = s; bi = idx; }
    }
    if (lane == 0) idxOut[t] = (float)bi;
    hardOut[(size_t)t * C_F4 + lane] = Cb[(size_t)bi * C_F4 + lane];
}

// ---------------------------------------------------------------------------
extern "C" void kernel_launch(void* const* d_in, const int* in_sizes, int n_in,
                              void* d_out, int out_size, void* d_ws, size_t ws_size,
                              hipStream_t stream) {
    const float* x  = (const float*)d_in[0];   // 32768 x 1024
    const float* cb = (const float*)d_in[1];   // 4096 x 256
    const float* w  = (const float*)d_in[2];   // 1024 x 256
    const float* bd = (const float*)d_in[3];   // 256

    float* zOut    = (float*)d_out;                    // 32768 x 256
    float* idxOut  = zOut + (size_t)NT * CD;           // 32768 (as float values)
    float* hardOut = idxOut + NT;                      // 32768 x 256

    float*  hn2   = (float*)d_ws;                            // 16 KB
    int4*   cands = (int4*)((char*)d_ws + 16384);            // 512 KB
    ushort* cbb   = (ushort*)((char*)d_ws + 16384 + 524288); // 2 MB bf16 codebook

    k0_prep<<<NC / 4, 256, 0, stream>>>((const float4*)cb, hn2, cbb);
    k1_gemm1<<<(NT / 128) * (CD / 128), 256, 0, stream>>>((const float4*)x,
                                                          (const float4*)w,
                                                          (float4*)zOut);
    k1b_norm<<<NT / 4, 256, 0, stream>>>((float4*)zOut, (const float4*)bd);
    k2_mfma<<<NT / 64, 256, 0, stream>>>(zOut, cbb, hn2, cands);
    k3_refine<<<NT / 4, 256, 0, stream>>>((const float4*)zOut, (const float4*)cb,
                                          cands, idxOut, (float4*)hardOut);
}

// Round 6
// 2068.280 us; speedup vs baseline: 2.9028x; 1.3123x over previous
//
#include <hip/hip_runtime.h>
#include <math.h>
#include <stdint.h>

#define NT 32768
#define DM 1024
#define NC 4096
#define CD 256

#define X_F4 (DM/4)
#define W_F4 (CD/4)
#define Z_F4 (CD/4)
#define C_F4 (CD/4)

#define GLOBAL_AS __attribute__((address_space(1)))
#define LDS_AS    __attribute__((address_space(3)))

typedef __attribute__((ext_vector_type(8))) short bf16x8;
typedef __attribute__((ext_vector_type(4))) float floatx4;

__device__ __forceinline__ unsigned short f2bf(float f) {
    union { float f; uint32_t u; } v; v.f = f;
    uint32_t u = v.u;
    u += 0x7FFFu + ((u >> 16) & 1u);   // RN-even
    return (unsigned short)(u >> 16);
}

// ---------------------------------------------------------------------------
// K0: per-code prep: hn2[code] = 0.5*||c||^2 - 2, bf16 codebook copy.
// ---------------------------------------------------------------------------
__global__ __launch_bounds__(256) void k0_prep(const float4* __restrict__ cb,
                                               float* __restrict__ hn2,
                                               ushort* __restrict__ cbb) {
    int wid = threadIdx.x >> 6, lane = threadIdx.x & 63;
    int code = blockIdx.x * 4 + wid;
    float4 c = cb[(size_t)code * C_F4 + lane];
    ushort4 h;
    h.x = f2bf(c.x); h.y = f2bf(c.y); h.z = f2bf(c.z); h.w = f2bf(c.w);
    ((ushort4*)cbb)[(size_t)code * 64 + lane] = h;
    float ss = c.x*c.x + c.y*c.y + c.z*c.z + c.w*c.w;
    #pragma unroll
    for (int m = 32; m >= 1; m >>= 1) ss += __shfl_xor(ss, m, 64);
    if (lane == 0) hn2[code] = 0.5f * ss - 2.0f;
}

// ---------------------------------------------------------------------------
// K1: z_pre = x @ W_down.
// 128x128 block, 256 threads, 8x8/thread, two-level fp32 accumulation
// (numerics proven rounds 3-5). Staging: global_load_lds width-16 DMA,
// double-buffered, ONE barrier/tile — zero staging VGPRs (round-5's VGPR
// prefetch pushed demand to ~260 -> spill). PLAIN __launch_bounds__(256):
// the (,2) form hard-caps arch VGPRs at 128 on this toolchain (rounds 3/4).
// A-swizzle folded into DMA *source* address (LDS dest must be
// lane-contiguous); DMA path validated correct in round 3.
// ---------------------------------------------------------------------------
__global__ __launch_bounds__(256) void k1_gemm1(const float4* __restrict__ X,
                                                const float4* __restrict__ W,
                                                float4* __restrict__ Zp) {
    __shared__ float4 Abuf[2][1024];  // 128 rows x 8 f4 (32 k), swizzled
    __shared__ float4 Bbuf[2][1024];  // 32 k x 32 f4 (128 cols), natural

    int tid  = threadIdx.x;
    int wid  = tid >> 6, lane = tid & 63;
    int tg   = ((wid & 1) << 3) | (lane & 7);    // row-group 0..15 (8 rows)
    int cg   = ((wid >> 1) << 3) | (lane >> 3);  // col-group 0..15 (8 cols)
    int mb   = blockIdx.x >> 1, nb = blockIdx.x & 1;
    int m0   = mb * 128;

    auto dma_tile = [&](int kt, int buf) {
        #pragma unroll
        for (int jj = 0; jj < 4; ++jj) {
            int v = jj * 256 + wid * 64 + lane;
            int row = v >> 3;
            int kv4 = (v & 7) ^ ((row >> 3) & 7);          // inverse swizzle on source
            const float4* gp = &X[(size_t)(m0 + row) * X_F4 + kt * 8 + kv4];
            __builtin_amdgcn_global_load_lds(
                (const GLOBAL_AS uint32_t*)gp,
                (LDS_AS uint32_t*)&Abuf[buf][jj * 256 + wid * 64], 16, 0, 0);
        }
        #pragma unroll
        for (int jj = 0; jj < 4; ++jj) {
            int v = jj * 256 + wid * 64 + lane;
            int kk = v >> 5, cv4 = v & 31;
            const float4* gp = &W[(size_t)(kt * 32 + kk) * W_F4 + nb * 32 + cv4];
            __builtin_amdgcn_global_load_lds(
                (const GLOBAL_AS uint32_t*)gp,
                (LDS_AS uint32_t*)&Bbuf[buf][jj * 256 + wid * 64], 16, 0, 0);
        }
    };

    float acc[8][8];
    #pragma unroll
    for (int i = 0; i < 8; ++i)
        #pragma unroll
        for (int j = 0; j < 8; ++j) acc[i][j] = 0.0f;

    dma_tile(0, 0);

    for (int kt = 0; kt < 32; ++kt) {
        __syncthreads();                      // drains tile kt's DMA (vmcnt) + buffer handoff
        if (kt < 31) dma_tile(kt + 1, (kt + 1) & 1);   // lands during compute below

        const float4* As = Abuf[kt & 1];
        const float4* Bs = Bbuf[kt & 1];

        float facc[8][8];
        #pragma unroll
        for (int i = 0; i < 8; ++i)
            #pragma unroll
            for (int j = 0; j < 8; ++j) facc[i][j] = 0.0f;

        #pragma unroll
        for (int q = 0; q < 8; ++q) {
            float4 a[8];
            #pragma unroll
            for (int i = 0; i < 8; ++i)
                a[i] = As[(tg * 8 + i) * 8 + (q ^ (tg & 7))];
            float4 b[4];
            #pragma unroll
            for (int p = 0; p < 4; ++p)
                b[p] = Bs[(q * 4 + p) * 32 + cg * 2];
            #pragma unroll
            for (int i = 0; i < 8; ++i) {
                facc[i][0] += a[i].x*b[0].x + a[i].y*b[1].x + a[i].z*b[2].x + a[i].w*b[3].x;
                facc[i][1] += a[i].x*b[0].y + a[i].y*b[1].y + a[i].z*b[2].y + a[i].w*b[3].y;
                facc[i][2] += a[i].x*b[0].z + a[i].y*b[1].z + a[i].z*b[2].z + a[i].w*b[3].z;
                facc[i][3] += a[i].x*b[0].w + a[i].y*b[1].w + a[i].z*b[2].w + a[i].w*b[3].w;
            }
            #pragma unroll
            for (int p = 0; p < 4; ++p)
                b[p] = Bs[(q * 4 + p) * 32 + cg * 2 + 1];
            #pragma unroll
            for (int i = 0; i < 8; ++i) {
                facc[i][4] += a[i].x*b[0].x + a[i].y*b[1].x + a[i].z*b[2].x + a[i].w*b[3].x;
                facc[i][5] += a[i].x*b[0].y + a[i].y*b[1].y + a[i].z*b[2].y + a[i].w*b[3].y;
                facc[i][6] += a[i].x*b[0].z + a[i].y*b[1].z + a[i].z*b[2].z + a[i].w*b[3].z;
                facc[i][7] += a[i].x*b[0].w + a[i].y*b[1].w + a[i].z*b[2].w + a[i].w*b[3].w;
            }
        }
        #pragma unroll
        for (int i = 0; i < 8; ++i)
            #pragma unroll
            for (int j = 0; j < 8; ++j) acc[i][j] += facc[i][j];
    }

    #pragma unroll
    for (int i = 0; i < 8; ++i) {
        int row = m0 + tg * 8 + i;
        float4 o0, o1;
        o0.x = acc[i][0]; o0.y = acc[i][1]; o0.z = acc[i][2]; o0.w = acc[i][3];
        o1.x = acc[i][4]; o1.y = acc[i][5]; o1.z = acc[i][6]; o1.w = acc[i][7];
        Zp[(size_t)row * Z_F4 + nb * 32 + cg * 2]     = o0;
        Zp[(size_t)row * Z_F4 + nb * 32 + cg * 2 + 1] = o1;
    }
}

// ---------------------------------------------------------------------------
// K1b: z = (z_pre + b) / (||z_pre + b|| + 1e-6) (unchanged)
// ---------------------------------------------------------------------------
__global__ __launch_bounds__(256) void k1b_norm(float4* __restrict__ Z,
                                                const float4* __restrict__ bias) {
    int wid = threadIdx.x >> 6, lane = threadIdx.x & 63;
    int t = blockIdx.x * 4 + wid;
    float4 b = bias[lane];
    float4 z = Z[(size_t)t * Z_F4 + lane];
    z.x += b.x; z.y += b.y; z.z += b.z; z.w += b.w;
    double ss = (double)z.x*z.x + (double)z.y*z.y + (double)z.z*z.z + (double)z.w*z.w;
    #pragma unroll
    for (int m = 32; m >= 1; m >>= 1) ss += __shfl_xor(ss, m, 64);
    float inv = 1.0f / ((float)sqrt(ss) + 1e-6f);
    z.x *= inv; z.y *= inv; z.z *= inv; z.w *= inv;
    Z[(size_t)t * Z_F4 + lane] = z;
}

// ---------------------------------------------------------------------------
// K2: bf16 MFMA candidate scoring (unchanged from round 5 — proven).
// ---------------------------------------------------------------------------
__global__ __launch_bounds__(256) void k2_mfma(const float* __restrict__ Z,
                                               const ushort* __restrict__ Cbb,
                                               const float* __restrict__ hn2g,
                                               int4* __restrict__ cands) {
    __shared__ __align__(16) char lds[32768 + 256];

    int tid  = threadIdx.x;
    int w    = tid >> 6;
    int lane = tid & 63;
    int c    = lane & 15, q = lane >> 4;
    int t0   = blockIdx.x * 64;

    bf16x8 A[4][8];
    #pragma unroll
    for (int mi = 0; mi < 4; ++mi) {
        #pragma unroll
        for (int ks = 0; ks < 8; ++ks) {
            const float* zp = Z + (size_t)(t0 + mi * 16 + c) * CD + ks * 32 + q * 8;
            float4 f0 = *(const float4*)zp;
            float4 f1 = *(const float4*)(zp + 4);
            bf16x8 a;
            a[0] = (short)f2bf(f0.x); a[1] = (short)f2bf(f0.y);
            a[2] = (short)f2bf(f0.z); a[3] = (short)f2bf(f0.w);
            a[4] = (short)f2bf(f1.x); a[5] = (short)f2bf(f1.y);
            a[6] = (short)f2bf(f1.z); a[7] = (short)f2bf(f1.w);
            A[mi][ks] = a;
        }
    }

    int baddr[8];
    #pragma unroll
    for (int ks = 0; ks < 8; ++ks)
        baddr[ks] = (w * 16 + c) * 512 + ((((ks * 4 + q) ^ c)) << 4);
    int hnaddr = 32768 + (w * 16 + c) * 4;

    auto issue_loads = [&](int ct, bf16x8* g, float& hnr) {
        #pragma unroll
        for (int jj = 0; jj < 8; ++jj) {
            int v = jj * 256 + tid;
            int row = v >> 5, ch = v & 31;
            int grow = ct * 64 + row; if (grow < 1) grow = 1;
            g[jj] = *(const bf16x8*)(Cbb + (size_t)grow * CD + ch * 8);
        }
        if (tid < 64) {
            int gc = ct * 64 + tid; if (gc < 1) gc = 1;
            hnr = hn2g[gc];
        }
    };
    auto write_lds = [&](const bf16x8* g, float hnr) {
        #pragma unroll
        for (int jj = 0; jj < 8; ++jj) {
            int v = jj * 256 + tid;
            int row = v >> 5, ch = v & 31;
            *(bf16x8*)(lds + row * 512 + ((ch ^ (row & 15)) << 4)) = g[jj];
        }
        if (tid < 64) *(float*)(lds + 32768 + tid * 4) = hnr;
    };

    uint32_t K1[16], K2[16];
    #pragma unroll
    for (int i = 0; i < 16; ++i) { K1[i] = 0u; K2[i] = 0u; }

    bf16x8 g[8]; float hnr = 0.0f;
    issue_loads(0, g, hnr);
    write_lds(g, hnr);

    for (int ct = 0; ct < 64; ++ct) {
        __syncthreads();
        bf16x8 g2[8]; float hnr2 = 0.0f;
        if (ct < 63) issue_loads(ct + 1, g2, hnr2);

        floatx4 C[4];
        #pragma unroll
        for (int mi = 0; mi < 4; ++mi) C[mi] = (floatx4){0.f, 0.f, 0.f, 0.f};

        #pragma unroll
        for (int ks = 0; ks < 8; ++ks) {
            bf16x8 Bf = *(const bf16x8*)(lds + baddr[ks]);
            #pragma unroll
            for (int mi = 0; mi < 4; ++mi)
                C[mi] = __builtin_amdgcn_mfma_f32_16x16x32_bf16(A[mi][ks], Bf, C[mi], 0, 0, 0);
        }

        float hv = *(const float*)(lds + hnaddr);
        #pragma unroll
        for (int mi = 0; mi < 4; ++mi) {
            #pragma unroll
            for (int r = 0; r < 4; ++r) {
                float sp = C[mi][r] - hv;
                union { float f; uint32_t u; } uv; uv.f = sp;
                uint32_t key = (uv.u & 0xFFFFFFC0u) | (uint32_t)ct;
                int i = mi * 4 + r;
                uint32_t lo = key < K1[i] ? key : K1[i];
                K1[i] = key > K1[i] ? key : K1[i];
                K2[i] = lo > K2[i] ? lo : K2[i];
            }
        }

        __syncthreads();
        if (ct < 63) write_lds(g2, hnr2);
    }

    __syncthreads();
    uint32_t* M = (uint32_t*)lds;
    #pragma unroll
    for (int mi = 0; mi < 4; ++mi) {
        #pragma unroll
        for (int r = 0; r < 4; ++r) {
            int tok = mi * 16 + q * 4 + r;
            int base = ((tok * 4 + w) * 16 + c) * 2;
            M[base]     = K1[mi * 4 + r];
            M[base + 1] = K2[mi * 4 + r];
        }
    }
    __syncthreads();
    if (tid < 64) {
        int tok = tid;
        uint32_t bk0 = 0, bk1 = 0, bk2 = 0, bk3 = 0;
        int      bp0 = 0, bp1 = 0, bp2 = 0, bp3 = 0;
        for (int e = 0; e < 128; ++e) {
            uint32_t key = M[tok * 128 + e];
            int pos = e >> 1;
            if (key > bk0) {
                bk3 = bk2; bp3 = bp2; bk2 = bk1; bp2 = bp1;
                bk1 = bk0; bp1 = bp0; bk0 = key; bp0 = pos;
            } else if (key > bk1) {
                bk3 = bk2; bp3 = bp2; bk2 = bk1; bp2 = bp1; bk1 = key; bp1 = pos;
            } else if (key > bk2) {
                bk3 = bk2; bp3 = bp2; bk2 = key; bp2 = pos;
            } else if (key > bk3) {
                bk3 = key; bp3 = pos;
            }
        }
        int4 out;
        out.x = (int)(bk0 & 63u) * 64 + bp0;
        out.y = (int)(bk1 & 63u) * 64 + bp1;
        out.z = (int)(bk2 & 63u) * 64 + bp2;
        out.w = (int)(bk3 & 63u) * 64 + bp3;
        cands[t0 + tok] = out;
    }
}

// ---------------------------------------------------------------------------
// K3: f64 re-rank of 4 candidates (unchanged).
// ---------------------------------------------------------------------------
__global__ __launch_bounds__(256) void k3_refine(const float4* __restrict__ Z,
                                                 const float4* __restrict__ Cb,
                                                 const int4* __restrict__ cands,
                                                 float* __restrict__ idxOut,
                                                 float4* __restrict__ hardOut) {
    int wid = threadIdx.x >> 6, lane = threadIdx.x & 63;
    int t = blockIdx.x * 4 + wid;
    int4 cd = cands[t];
    int cc[4] = {cd.x, cd.y, cd.z, cd.w};
    float4 z = Z[(size_t)t * Z_F4 + lane];
    double best = -1.0e300;
    int bi = NC;
    #pragma unroll
    for (int e = 0; e < 4; ++e) {
        int idx = cc[e];
        float4 cf = Cb[(size_t)idx * C_F4 + lane];
        double dot = (double)z.x*cf.x + (double)z.y*cf.y + (double)z.z*cf.z + (double)z.w*cf.w;
        double nrm = (double)cf.x*cf.x + (double)cf.y*cf.y + (double)cf.z*cf.z + (double)cf.w*cf.w;
        #pragma unroll
        for (int m = 32; m >= 1; m >>= 1) {
            dot += __shfl_xor(dot, m, 64);
            nrm += __shfl_xor(nrm, m, 64);
        }
        double s = dot - 0.5 * nrm;
        if (idx >= 1 && (s > best || (s == best && idx < bi))) { best = s; bi = idx; }
    }
    if (lane == 0) idxOut[t] = (float)bi;
    hardOut[(size_t)t * C_F4 + lane] = Cb[(size_t)bi * C_F4 + lane];
}

// ---------------------------------------------------------------------------
extern "C" void kernel_launch(void* const* d_in, const int* in_sizes, int n_in,
                              void* d_out, int out_size, void* d_ws, size_t ws_size,
                              hipStream_t stream) {
    const float* x  = (const float*)d_in[0];   // 32768 x 1024
    const float* cb = (const float*)d_in[1];   // 4096 x 256
    const float* w  = (const float*)d_in[2];   // 1024 x 256
    const float* bd = (const float*)d_in[3];   // 256

    float* zOut    = (float*)d_out;                    // 32768 x 256
    float* idxOut  = zOut + (size_t)NT * CD;           // 32768 (as float values)
    float* hardOut = idxOut + NT;                      // 32768 x 256

    float*  hn2   = (float*)d_ws;                            // 16 KB
    int4*   cands = (int4*)((char*)d_ws + 16384);            // 512 KB
    ushort* cbb   = (ushort*)((char*)d_ws + 16384 + 524288); // 2 MB bf16 codebook

    k0_prep<<<NC / 4, 256, 0, stream>>>((const float4*)cb, hn2, cbb);
    k1_gemm1<<<(NT / 128) * (CD / 128), 256, 0, stream>>>((const float4*)x,
                                                          (const float4*)w,
                                                          (float4*)zOut);
    k1b_norm<<<NT / 4, 256, 0, stream>>>((float4*)zOut, (const float4*)bd);
    k2_mfma<<<NT / 64, 256, 0, stream>>>(zOut, cbb, hn2, cands);
    k3_refine<<<NT / 4, 256, 0, stream>>>((const float4*)zOut, (const float4*)cb,
                                          cands, idxOut, (float4*)hardOut);
}